// Round 4
// baseline (136.640 us; speedup 1.0000x reference)
//
#include <hip/hip_runtime.h>
#include <math.h>

#define NB 8
#define NH 8
#define SEQ 512
#define DK 64
#define NC 5
#define D_IN 262144   // 8*512*64 per batch
#define OUT_SCORE (NB*NH*SEQ*SEQ)   // 16777216
#define PROJ_BLOCKS 128

typedef short short8 __attribute__((ext_vector_type(8)));
typedef float f32x16 __attribute__((ext_vector_type(16)));

// fp32 -> bf16 (RTNE), bit pattern in a short
__device__ __forceinline__ short f2bf(float f) {
  unsigned u = __float_as_uint(f);
  u += 0x7fffu + ((u >> 16) & 1u);
  return (short)(u >> 16);
}
__device__ __forceinline__ short8 pack8(float4 a, float4 b) {
  short8 r;
  r[0] = f2bf(a.x); r[1] = f2bf(a.y); r[2] = f2bf(a.z); r[3] = f2bf(a.w);
  r[4] = f2bf(b.x); r[5] = f2bf(b.y); r[6] = f2bf(b.z); r[7] = f2bf(b.w);
  return r;
}

// ------- Kernel A: per-block partials of ck[b][c] (proven ~4 us) -------
__global__ __launch_bounds__(256) void proj_kernel(const float* __restrict__ K,
                                                   const float* __restrict__ Wp,
                                                   float* __restrict__ part) {
  const float4* Wp4 = (const float4*)Wp;
  float acc[NB][NC];
#pragma unroll
  for (int b = 0; b < NB; ++b)
#pragma unroll
    for (int c = 0; c < NC; ++c) acc[b][c] = 0.f;

#pragma unroll
  for (int it = 0; it < 2; ++it) {
    int i4 = blockIdx.x * 512 + it * 256 + threadIdx.x;  // float4 idx over D_IN
    float w[20];
#pragma unroll
    for (int t = 0; t < 5; ++t) {
      float4 v = Wp4[i4 * 5 + t];
      w[4*t+0] = v.x; w[4*t+1] = v.y; w[4*t+2] = v.z; w[4*t+3] = v.w;
    }
#pragma unroll
    for (int b = 0; b < NB; ++b) {
      float4 kv = ((const float4*)(K + (size_t)b * D_IN))[i4];
      float ke[4] = {kv.x, kv.y, kv.z, kv.w};
#pragma unroll
      for (int e = 0; e < 4; ++e)
#pragma unroll
        for (int c = 0; c < NC; ++c)
          acc[b][c] = fmaf(ke[e], w[5*e + c], acc[b][c]);
    }
  }

  __shared__ float red[4][NB * NC];
  int wave = threadIdx.x >> 6;
  int lane = threadIdx.x & 63;
#pragma unroll
  for (int bc = 0; bc < NB * NC; ++bc) {
    float v = acc[bc / NC][bc % NC];
#pragma unroll
    for (int off = 32; off > 0; off >>= 1) v += __shfl_down(v, off);
    if (lane == 0) red[wave][bc] = v;
  }
  __syncthreads();
  if (threadIdx.x < NB * NC)
    part[blockIdx.x * (NB * NC) + threadIdx.x] =
        red[0][threadIdx.x] + red[1][threadIdx.x] +
        red[2][threadIdx.x] + red[3][threadIdx.x];
}

// ---- Kernel B (fused): redundant small-phase + 128q x 64k score tiles ----
// Store-path overhaul (R4): NT dropped (suspected -4.5us regression from R2:
// nt bypasses L2 write-coalescing on 32 scalar dword stores/thread). Epilogue
// now does qc-fmax in-register, transposes each wave's 32q x 64k fp32 result
// through its private 8 KB LDS quarter (Qs/Ks dead by then; full 32 KB union)
// and stores 8x dwordx4/thread: each store instr = 4 rows x 256 B contiguous.
// LDS total unchanged 32768 B -> 5 blocks/CU.
#define LDSTRIDE 72   // shorts; 144 B rows: 16B-aligned, uniform b128 bank spread
__global__ __launch_bounds__(256) void score_kernel(
    const float* __restrict__ Q, const float* __restrict__ K,
    const float* __restrict__ part, const float* __restrict__ bp,
    const float* __restrict__ Wq, const float* __restrict__ bq,
    const float* __restrict__ Wk, const float* __restrict__ bk,
    float* __restrict__ out) {
  __shared__ __align__(16) char smem[32768];
  short* Qs = (short*)smem;                  // 128*72*2 = 18432 B
  short* Ks = (short*)(smem + 18432);        //  64*72*2 =  9216 B
  float* sp = (float*)(smem + 27648);        //  1280 floats = 5120 B
  float* trbuf = (float*)smem;               // epilogue: 4 waves x 2048 floats
  // sp union layout:
  //   phase S (small):  means_sh = sp[0..1023]  ([2][512])
  //                     inds     = (int*)&sp[1024] (8)
  //                     cs4      = &sp[1032] ([4][40], row0 doubles as colsum)
  //                     cq       = &sp[1192] ([8][5])
  //                     ckk      = &sp[1232] ([8][5])
  //                     ce       = &sp[1272] (8)
  //   phase E (epilogue): qcbuf = sp[0..1279]  (4 waves x 32 x 10)
  float* means_sh = sp;
  int*   inds_sh  = (int*)&sp[1024];
  float* cs4      = &sp[1032];
  float* cq_sh    = &sp[1192];
  float* ckk_sh   = &sp[1232];
  float* ce_sh    = &sp[1272];

  // XCD-chunked tile decode (2048 = 8 XCD x 256, bijective)
  const int swz = (blockIdx.x & 7) * 256 + (blockIdx.x >> 3);
  const int kblk = (swz & 7) << 6;           // fastest within chunk: 8 kblks
  const int grp  = swz >> 3;                 // 0..255
  const int qblk = (grp & 3) << 7;           // then 4 qblks
  const int bh   = grp >> 2;                 // 8 consecutive bh per XCD chunk
  const int h  = bh & 7;
  const int tid = threadIdx.x;
  const int w = tid >> 6, lane = tid & 63;
  const int lo5 = lane & 31, hi = lane >> 5;
  const int wq = w << 5;                     // wave's q offset in tile (0/32/64/96)

  const float* Qg = Q + (size_t)bh * (SEQ * DK) + (size_t)qblk * DK;
  const float* Kg = K + (size_t)bh * (SEQ * DK) + (size_t)kblk * DK;

  // ---- stage tiles FIRST (fp32 -> bf16): HBM loads issue before small-phase
#pragma unroll
  for (int i = 0; i < 4; ++i) {              // Q: 128 rows x 8 chunks
    int f8 = i * 256 + tid;
    int row = f8 >> 3, c8 = f8 & 7;
    const float4* qp = (const float4*)(Qg + row * DK + c8 * 8);
    *(short8*)&Qs[row * LDSTRIDE + c8 * 8] = pack8(qp[0], qp[1]);
  }
#pragma unroll
  for (int i = 0; i < 2; ++i) {              // K: 64 rows x 8 chunks
    int f8 = i * 256 + tid;
    int row = f8 >> 3, c8 = f8 & 7;
    const float4* kp = (const float4*)(Kg + row * DK + c8 * 8);
    *(short8*)&Ks[row * LDSTRIDE + c8 * 8] = pack8(kp[0], kp[1]);
  }

  // ---- small-phase: colsum of part (L2-warm) -> softmax -> inds/means ----
  if (tid < 160) {
    int sl = tid / 40, c = tid - sl * 40;
    float s = 0.f;
#pragma unroll
    for (int i = 0; i < 32; ++i) s += part[(sl * 32 + i) * (NB * NC) + c];
    cs4[sl * 40 + c] = s;
  }
  __syncthreads();
  if (tid < 40)
    cs4[tid] = cs4[tid] + cs4[40 + tid] + cs4[80 + tid] + cs4[120 + tid];
  __syncthreads();
  if (tid < NB) {
    float cp[NC], zq[NC], zk[NC];
#pragma unroll
    for (int c = 0; c < NC; ++c) cp[c] = cs4[tid * NC + c] + bp[c];
#pragma unroll
    for (int c = 0; c < NC; ++c) { zq[c] = bq[c]; zk[c] = bk[c]; }
#pragma unroll
    for (int j = 0; j < NC; ++j)
#pragma unroll
      for (int c = 0; c < NC; ++c) {
        zq[c] = fmaf(cp[j], Wq[j * NC + c], zq[c]);
        zk[c] = fmaf(cp[j], Wk[j * NC + c], zk[c]);
      }
    float m = zq[0];
#pragma unroll
    for (int c = 1; c < NC; ++c) m = fmaxf(m, zq[c]);
    float e[NC], s = 0.f;
#pragma unroll
    for (int c = 0; c < NC; ++c) { e[c] = expf(zq[c] - m); s += e[c]; }
    float inv = 1.f / s;
    float p[NC];
#pragma unroll
    for (int c = 0; c < NC; ++c) { p[c] = e[c] * inv; cq_sh[tid * NC + c] = p[c]; }
    int am = 0; float bv = p[0];
#pragma unroll
    for (int c = 1; c < NC; ++c) if (p[c] > bv) { bv = p[c]; am = c; }
    inds_sh[tid] = am;
    float se = 0.f;
#pragma unroll
    for (int c = 0; c < NC; ++c) se += expf(p[c] - bv);
    float lse = bv + logf(se);
    float ceb = 0.f;
#pragma unroll
    for (int c = 0; c < NC; ++c) ceb -= p[c] * (p[c] - lse);
    ce_sh[tid] = ceb;
    m = zk[0];
#pragma unroll
    for (int c = 1; c < NC; ++c) m = fmaxf(m, zk[c]);
    s = 0.f;
#pragma unroll
    for (int c = 0; c < NC; ++c) { e[c] = expf(zk[c] - m); s += e[c]; }
    inv = 1.f / s;
#pragma unroll
    for (int c = 0; c < NC; ++c) ckk_sh[tid * NC + c] = e[c] * inv;
  }
  __syncthreads();

  // ---- loss: block 0 thread 0 only ----
  if (blockIdx.x == 0 && tid == 0) {
    float mu[NC];
#pragma unroll
    for (int c = 0; c < NC; ++c) {
      float sm = 0.f;
      for (int b = 0; b < NB; ++b) sm += cq_sh[b * NC + c];
      mu[c] = sm * 0.125f;
    }
    float loss_lp = 0.f;
#pragma unroll
    for (int c = 0; c < NC; ++c) {
      float sm = 0.f;
      for (int b = 0; b < NB; ++b) sm += ckk_sh[b * NC + c];
      float mk = sm * 0.125f;
      float var = 0.f;
      for (int b = 0; b < NB; ++b) {
        float d = ckk_sh[b * NC + c] - mk;
        var += d * d;
      }
      var *= (1.f / 7.f);                 // ddof=1
      float sd = sqrtf(var);
      float sigma = log1pf(expf(sd));     // softplus
      float ls = logf(sigma);
      for (int b = 0; b < NB; ++b) {
        float z = (ckk_sh[b * NC + c] - mu[c]) / sigma;
        loss_lp += -0.5f * z * z - ls - 0.91893853320467274f;
      }
    }
    float ce = 0.f;
    for (int b = 0; b < NB; ++b) ce += ce_sh[b];
    ce *= 0.125f;
    out[OUT_SCORE] = -(loss_lp / 40.f) + ce;
  }

  // ---- means slice for this head's 2 clusters (K rows are L2/L3-hot) ----
  const int cmin = (5 * h) >> 3;
  const int cmax = (5 * h + 4) >> 3;
  for (int idx = tid; idx < 2 * 512; idx += 256) {
    int c2 = idx >> 9, j = idx & 511;
    int c = c2 ? cmax : cmin;
    float sm = 0.f;
#pragma unroll
    for (int b = 0; b < NB; ++b)
      if (inds_sh[b] != c + 1) sm += K[(size_t)b * D_IN + j];
    means_sh[idx] = sm * 0.125f;
  }
  __syncthreads();

  // ---- means A-fragment (rows 0..7 = cmin, 8..15 = cmax, 16..31 zero) ----
  short8 mfrag[4];
#pragma unroll
  for (int s = 0; s < 4; ++s) {
    float4 a = {0.f, 0.f, 0.f, 0.f}, b = {0.f, 0.f, 0.f, 0.f};
    if (lo5 < 16) {
      const float* mp = means_sh + (lo5 >> 3 << 9) + (lo5 & 7) * 64 + s * 16 + hi * 8;
      a = *(const float4*)mp;
      b = *(const float4*)(mp + 4);
    }
    mfrag[s] = pack8(a, b);
  }

  __syncthreads();   // mfrag/means reads done; qcbuf may now overwrite sp

  f32x16 zero;
#pragma unroll
  for (int x = 0; x < 16; ++x) zero[x] = 0.f;

  // ---- MFMA loop: 2 acc (k 0-31 / 32-63) + 1 qc per k-step ----
  f32x16 acc0 = zero, acc1 = zero, aq = zero;
#pragma unroll
  for (int s = 0; s < 4; ++s) {
    int co = s * 16 + hi * 8;
    short8 a  = *(const short8*)&Qs[(wq + lo5)  * LDSTRIDE + co];
    short8 b0 = *(const short8*)&Ks[lo5         * LDSTRIDE + co];
    short8 b1 = *(const short8*)&Ks[(32 + lo5)  * LDSTRIDE + co];
    acc0 = __builtin_amdgcn_mfma_f32_32x32x16_bf16(a, b0, acc0, 0, 0, 0);
    acc1 = __builtin_amdgcn_mfma_f32_32x32x16_bf16(a, b1, acc1, 0, 0, 0);
    aq   = __builtin_amdgcn_mfma_f32_32x32x16_bf16(mfrag[s], a, aq, 0, 0, 0);
  }

  // ---- in-lane qc extraction -> wave-private LDS (no barrier needed) ----
  float* qcbuf = sp;
  {
    int qb = w * 320 + lo5 * 10 + 4 * hi;
    float2 p;
    p.x = fmaxf(aq[0], aq[4]) * 0.125f;
    p.y = fmaxf(aq[1], aq[5]) * 0.125f;
    *(float2*)&qcbuf[qb] = p;
    p.x = fmaxf(aq[2], aq[6]) * 0.125f;
    p.y = fmaxf(aq[3], aq[7]) * 0.125f;
    *(float2*)&qcbuf[qb + 2] = p;
  }

  // ---- qc-fmax in-register (same-wave qcbuf reads, no barrier) ----
  // k = kblk+lo5 and kblk+32+lo5 share (k&7) => same qc for both acc cols.
  const int r = lo5 & 7;
  const int qcb = w * 320 + r;
  float fin0[16], fin1[16];
#pragma unroll
  for (int g = 0; g < 4; ++g) {
#pragma unroll
    for (int e = 0; e < 4; ++e) {
      int reg = 4 * g + e;
      int ql = e + 8 * g + 4 * hi;           // q within wave's 32-row window
      float qc = qcbuf[qcb + ql * 10];
      fin0[reg] = fmaxf(acc0[reg] * 0.125f, qc);
      fin1[reg] = fmaxf(acc1[reg] * 0.125f, qc);
    }
  }

  // All qcbuf reads (sp region) and all MFMA ds_reads (Qs/Ks) are complete
  // across the block before trbuf overwrites the union.
  __syncthreads();

  // ---- wave-private transpose: 32q x 64k fp32 tile -> 8 KB LDS quarter ----
  float* trw = trbuf + (w << 11);            // 2048 floats per wave
#pragma unroll
  for (int g = 0; g < 4; ++g) {
#pragma unroll
    for (int e = 0; e < 4; ++e) {
      int reg = 4 * g + e;
      int ql = e + 8 * g + 4 * hi;
      trw[ql * 64 + lo5]      = fin0[reg];
      trw[ql * 64 + 32 + lo5] = fin1[reg];
    }
  }

  // ---- read back row-major, store dwordx4 (4 rows x 256 B per instr) ----
  float* ob = out + (size_t)bh * (SEQ * SEQ) + (size_t)(qblk + wq) * SEQ + kblk;
#pragma unroll
  for (int i = 0; i < 8; ++i) {
    int f = i * 64 + lane;                   // 0..511
    int q = f >> 4, j = f & 15;
    float4 v = *(const float4*)&trw[q * 64 + j * 4];
    *(float4*)&ob[(size_t)q * SEQ + j * 4] = v;
  }
}

extern "C" void kernel_launch(void* const* d_in, const int* in_sizes, int n_in,
                              void* d_out, int out_size, void* d_ws, size_t ws_size,
                              hipStream_t stream) {
  const float* Q  = (const float*)d_in[0];
  const float* K  = (const float*)d_in[1];
  const float* Wp = (const float*)d_in[2];
  const float* bp = (const float*)d_in[3];
  const float* Wq = (const float*)d_in[4];
  const float* bq = (const float*)d_in[5];
  const float* Wk = (const float*)d_in[6];
  const float* bk = (const float*)d_in[7];
  float* out = (float*)d_out;

  float* part = (float*)d_ws;                      // 128*40 partials

  proj_kernel<<<PROJ_BLOCKS, 256, 0, stream>>>(K, Wp, part);
  score_kernel<<<2048, 256, 0, stream>>>(Q, K, part, bp, Wq, bq, Wk, bk, out);
}

// Round 5
// 133.289 us; speedup vs baseline: 1.0251x; 1.0251x over previous
//
#include <hip/hip_runtime.h>
#include <math.h>

#define NB 8
#define NH 8
#define SEQ 512
#define DK 64
#define NC 5
#define D_IN 262144   // 8*512*64 per batch
#define OUT_SCORE (NB*NH*SEQ*SEQ)   // 16777216
#define PROJ_BLOCKS 128

typedef short short8 __attribute__((ext_vector_type(8)));
typedef float f32x16 __attribute__((ext_vector_type(16)));

// fp32 -> bf16 (RTNE), bit pattern in a short
__device__ __forceinline__ short f2bf(float f) {
  unsigned u = __float_as_uint(f);
  u += 0x7fffu + ((u >> 16) & 1u);
  return (short)(u >> 16);
}
__device__ __forceinline__ short8 pack8(float4 a, float4 b) {
  short8 r;
  r[0] = f2bf(a.x); r[1] = f2bf(a.y); r[2] = f2bf(a.z); r[3] = f2bf(a.w);
  r[4] = f2bf(b.x); r[5] = f2bf(b.y); r[6] = f2bf(b.z); r[7] = f2bf(b.w);
  return r;
}

// ------- Kernel A: per-block partials of ck[b][c] (proven ~4 us) -------
__global__ __launch_bounds__(256) void proj_kernel(const float* __restrict__ K,
                                                   const float* __restrict__ Wp,
                                                   float* __restrict__ part) {
  const float4* Wp4 = (const float4*)Wp;
  float acc[NB][NC];
#pragma unroll
  for (int b = 0; b < NB; ++b)
#pragma unroll
    for (int c = 0; c < NC; ++c) acc[b][c] = 0.f;

#pragma unroll
  for (int it = 0; it < 2; ++it) {
    int i4 = blockIdx.x * 512 + it * 256 + threadIdx.x;  // float4 idx over D_IN
    float w[20];
#pragma unroll
    for (int t = 0; t < 5; ++t) {
      float4 v = Wp4[i4 * 5 + t];
      w[4*t+0] = v.x; w[4*t+1] = v.y; w[4*t+2] = v.z; w[4*t+3] = v.w;
    }
#pragma unroll
    for (int b = 0; b < NB; ++b) {
      float4 kv = ((const float4*)(K + (size_t)b * D_IN))[i4];
      float ke[4] = {kv.x, kv.y, kv.z, kv.w};
#pragma unroll
      for (int e = 0; e < 4; ++e)
#pragma unroll
        for (int c = 0; c < NC; ++c)
          acc[b][c] = fmaf(ke[e], w[5*e + c], acc[b][c]);
    }
  }

  __shared__ float red[4][NB * NC];
  int wave = threadIdx.x >> 6;
  int lane = threadIdx.x & 63;
#pragma unroll
  for (int bc = 0; bc < NB * NC; ++bc) {
    float v = acc[bc / NC][bc % NC];
#pragma unroll
    for (int off = 32; off > 0; off >>= 1) v += __shfl_down(v, off);
    if (lane == 0) red[wave][bc] = v;
  }
  __syncthreads();
  if (threadIdx.x < NB * NC)
    part[blockIdx.x * (NB * NC) + threadIdx.x] =
        red[0][threadIdx.x] + red[1][threadIdx.x] +
        red[2][threadIdx.x] + red[3][threadIdx.x];
}

// ---- Kernel B (fused): redundant small-phase + 128q x 64k score tiles ----
// R5: ledger-driven revert. Keep the small-phase fusion (R3's proven -4.5us),
// restore R0's epilogue (plain scalar stores: 2x128B segments per wave instr,
// no NT, no LDS round-trip) and R0's grid mapping (bh fastest) — the config
// with the best implied score-kernel time (~24us) across R0-R4.
#define LDSTRIDE 72   // shorts; 144 B rows: 16B-aligned, uniform b128 bank spread
__global__ __launch_bounds__(256) void score_kernel(
    const float* __restrict__ Q, const float* __restrict__ K,
    const float* __restrict__ part, const float* __restrict__ bp,
    const float* __restrict__ Wq, const float* __restrict__ bq,
    const float* __restrict__ Wk, const float* __restrict__ bk,
    float* __restrict__ out) {
  __shared__ short Qs[128 * LDSTRIDE];       // 18432 B
  __shared__ short Ks[64 * LDSTRIDE];        //  9216 B
  __shared__ __align__(16) float sp[1280];   //  5120 B  => 32768 B total
  // sp union layout:
  //   phase S (small):  means_sh = sp[0..1023]  ([2][512])
  //                     inds     = (int*)&sp[1024] (8)
  //                     cs4      = &sp[1032] ([4][40], row0 doubles as colsum)
  //                     cq       = &sp[1192] ([8][5])
  //                     ckk      = &sp[1232] ([8][5])
  //                     ce       = &sp[1272] (8)
  //   phase E (epilogue): qcbuf = sp[0..1279]  (4 waves x 32 x 10)
  float* means_sh = sp;
  int*   inds_sh  = (int*)&sp[1024];
  float* cs4      = &sp[1032];
  float* cq_sh    = &sp[1192];
  float* ckk_sh   = &sp[1232];
  float* ce_sh    = &sp[1272];

  // R0 grid mapping: bh fastest (blockIdx.x), qblk=y, kblk=z
  const int bh   = blockIdx.x;
  const int qblk = blockIdx.y << 7;          // 0,128,256,384
  const int kblk = blockIdx.z << 6;          // 0..448 step 64
  const int h  = bh & 7;
  const int tid = threadIdx.x;
  const int w = tid >> 6, lane = tid & 63;
  const int lo5 = lane & 31, hi = lane >> 5;
  const int wq = w << 5;                     // wave's q offset in tile (0/32/64/96)

  const float* Qg = Q + (size_t)bh * (SEQ * DK) + (size_t)qblk * DK;
  const float* Kg = K + (size_t)bh * (SEQ * DK) + (size_t)kblk * DK;

  // ---- stage tiles FIRST (fp32 -> bf16): HBM loads issue before small-phase
#pragma unroll
  for (int i = 0; i < 4; ++i) {              // Q: 128 rows x 8 chunks
    int f8 = i * 256 + tid;
    int row = f8 >> 3, c8 = f8 & 7;
    const float4* qp = (const float4*)(Qg + row * DK + c8 * 8);
    *(short8*)&Qs[row * LDSTRIDE + c8 * 8] = pack8(qp[0], qp[1]);
  }
#pragma unroll
  for (int i = 0; i < 2; ++i) {              // K: 64 rows x 8 chunks
    int f8 = i * 256 + tid;
    int row = f8 >> 3, c8 = f8 & 7;
    const float4* kp = (const float4*)(Kg + row * DK + c8 * 8);
    *(short8*)&Ks[row * LDSTRIDE + c8 * 8] = pack8(kp[0], kp[1]);
  }

  // ---- small-phase: colsum of part (L2-warm) -> softmax -> inds/means ----
  if (tid < 160) {
    int sl = tid / 40, c = tid - sl * 40;
    float s = 0.f;
#pragma unroll
    for (int i = 0; i < 32; ++i) s += part[(sl * 32 + i) * (NB * NC) + c];
    cs4[sl * 40 + c] = s;
  }
  __syncthreads();
  if (tid < 40)
    cs4[tid] = cs4[tid] + cs4[40 + tid] + cs4[80 + tid] + cs4[120 + tid];
  __syncthreads();
  if (tid < NB) {
    float cp[NC], zq[NC], zk[NC];
#pragma unroll
    for (int c = 0; c < NC; ++c) cp[c] = cs4[tid * NC + c] + bp[c];
#pragma unroll
    for (int c = 0; c < NC; ++c) { zq[c] = bq[c]; zk[c] = bk[c]; }
#pragma unroll
    for (int j = 0; j < NC; ++j)
#pragma unroll
      for (int c = 0; c < NC; ++c) {
        zq[c] = fmaf(cp[j], Wq[j * NC + c], zq[c]);
        zk[c] = fmaf(cp[j], Wk[j * NC + c], zk[c]);
      }
    float m = zq[0];
#pragma unroll
    for (int c = 1; c < NC; ++c) m = fmaxf(m, zq[c]);
    float e[NC], s = 0.f;
#pragma unroll
    for (int c = 0; c < NC; ++c) { e[c] = expf(zq[c] - m); s += e[c]; }
    float inv = 1.f / s;
    float p[NC];
#pragma unroll
    for (int c = 0; c < NC; ++c) { p[c] = e[c] * inv; cq_sh[tid * NC + c] = p[c]; }
    int am = 0; float bv = p[0];
#pragma unroll
    for (int c = 1; c < NC; ++c) if (p[c] > bv) { bv = p[c]; am = c; }
    inds_sh[tid] = am;
    float se = 0.f;
#pragma unroll
    for (int c = 0; c < NC; ++c) se += expf(p[c] - bv);
    float lse = bv + logf(se);
    float ceb = 0.f;
#pragma unroll
    for (int c = 0; c < NC; ++c) ceb -= p[c] * (p[c] - lse);
    ce_sh[tid] = ceb;
    m = zk[0];
#pragma unroll
    for (int c = 1; c < NC; ++c) m = fmaxf(m, zk[c]);
    s = 0.f;
#pragma unroll
    for (int c = 0; c < NC; ++c) { e[c] = expf(zk[c] - m); s += e[c]; }
    inv = 1.f / s;
#pragma unroll
    for (int c = 0; c < NC; ++c) ckk_sh[tid * NC + c] = e[c] * inv;
  }
  __syncthreads();

  // ---- loss: block (bh=0,qblk=0,kblk=0) thread 0 only ----
  if (blockIdx.x == 0 && blockIdx.y == 0 && blockIdx.z == 0 && tid == 0) {
    float mu[NC];
#pragma unroll
    for (int c = 0; c < NC; ++c) {
      float sm = 0.f;
      for (int b = 0; b < NB; ++b) sm += cq_sh[b * NC + c];
      mu[c] = sm * 0.125f;
    }
    float loss_lp = 0.f;
#pragma unroll
    for (int c = 0; c < NC; ++c) {
      float sm = 0.f;
      for (int b = 0; b < NB; ++b) sm += ckk_sh[b * NC + c];
      float mk = sm * 0.125f;
      float var = 0.f;
      for (int b = 0; b < NB; ++b) {
        float d = ckk_sh[b * NC + c] - mk;
        var += d * d;
      }
      var *= (1.f / 7.f);                 // ddof=1
      float sd = sqrtf(var);
      float sigma = log1pf(expf(sd));     // softplus
      float ls = logf(sigma);
      for (int b = 0; b < NB; ++b) {
        float z = (ckk_sh[b * NC + c] - mu[c]) / sigma;
        loss_lp += -0.5f * z * z - ls - 0.91893853320467274f;
      }
    }
    float ce = 0.f;
    for (int b = 0; b < NB; ++b) ce += ce_sh[b];
    ce *= 0.125f;
    out[OUT_SCORE] = -(loss_lp / 40.f) + ce;
  }

  // ---- means slice for this head's 2 clusters (K rows are L2/L3-hot) ----
  const int cmin = (5 * h) >> 3;
  const int cmax = (5 * h + 4) >> 3;
  for (int idx = tid; idx < 2 * 512; idx += 256) {
    int c2 = idx >> 9, j = idx & 511;
    int c = c2 ? cmax : cmin;
    float sm = 0.f;
#pragma unroll
    for (int b = 0; b < NB; ++b)
      if (inds_sh[b] != c + 1) sm += K[(size_t)b * D_IN + j];
    means_sh[idx] = sm * 0.125f;
  }
  __syncthreads();

  // ---- means A-fragment (rows 0..7 = cmin, 8..15 = cmax, 16..31 zero) ----
  short8 mfrag[4];
#pragma unroll
  for (int s = 0; s < 4; ++s) {
    float4 a = {0.f, 0.f, 0.f, 0.f}, b = {0.f, 0.f, 0.f, 0.f};
    if (lo5 < 16) {
      const float* mp = means_sh + (lo5 >> 3 << 9) + (lo5 & 7) * 64 + s * 16 + hi * 8;
      a = *(const float4*)mp;
      b = *(const float4*)(mp + 4);
    }
    mfrag[s] = pack8(a, b);
  }

  __syncthreads();   // mfrag/means reads done; qcbuf may now overwrite sp

  f32x16 zero;
#pragma unroll
  for (int x = 0; x < 16; ++x) zero[x] = 0.f;

  // ---- MFMA loop: 2 acc (k 0-31 / 32-63) + 1 qc per k-step ----
  f32x16 acc0 = zero, acc1 = zero, aq = zero;
#pragma unroll
  for (int s = 0; s < 4; ++s) {
    int co = s * 16 + hi * 8;
    short8 a  = *(const short8*)&Qs[(wq + lo5)  * LDSTRIDE + co];
    short8 b0 = *(const short8*)&Ks[lo5         * LDSTRIDE + co];
    short8 b1 = *(const short8*)&Ks[(32 + lo5)  * LDSTRIDE + co];
    acc0 = __builtin_amdgcn_mfma_f32_32x32x16_bf16(a, b0, acc0, 0, 0, 0);
    acc1 = __builtin_amdgcn_mfma_f32_32x32x16_bf16(a, b1, acc1, 0, 0, 0);
    aq   = __builtin_amdgcn_mfma_f32_32x32x16_bf16(mfrag[s], a, aq, 0, 0, 0);
  }

  // ---- in-lane qc extraction -> wave-private LDS (no barrier needed) ----
  float* qcbuf = sp;
  {
    int qb = w * 320 + lo5 * 10 + 4 * hi;
    float2 p;
    p.x = fmaxf(aq[0], aq[4]) * 0.125f;
    p.y = fmaxf(aq[1], aq[5]) * 0.125f;
    *(float2*)&qcbuf[qb] = p;
    p.x = fmaxf(aq[2], aq[6]) * 0.125f;
    p.y = fmaxf(aq[3], aq[7]) * 0.125f;
    *(float2*)&qcbuf[qb + 2] = p;
  }

  // ---- epilogue: qc from LDS (same-wave), plain scalar stores (full lines) ----
  // k = kblk+lo5 and kblk+32+lo5 share (k&7) => same qc for both acc cols.
  float* ob = out + (size_t)bh * (SEQ * SEQ);
  const int kc0 = kblk + lo5;
  const int r = lo5 & 7;
  const int qcb = w * 320 + r;
#pragma unroll
  for (int g = 0; g < 4; ++g) {
#pragma unroll
    for (int e = 0; e < 4; ++e) {
      int reg = 4 * g + e;
      int ql = e + 8 * g + 4 * hi;           // q within wave's 32-row window
      float qc = qcbuf[qcb + ql * 10];
      int qrow = qblk + wq + ql;
      ob[(size_t)qrow * SEQ + kc0]      = fmaxf(acc0[reg] * 0.125f, qc);
      ob[(size_t)qrow * SEQ + kc0 + 32] = fmaxf(acc1[reg] * 0.125f, qc);
    }
  }
}

extern "C" void kernel_launch(void* const* d_in, const int* in_sizes, int n_in,
                              void* d_out, int out_size, void* d_ws, size_t ws_size,
                              hipStream_t stream) {
  const float* Q  = (const float*)d_in[0];
  const float* K  = (const float*)d_in[1];
  const float* Wp = (const float*)d_in[2];
  const float* bp = (const float*)d_in[3];
  const float* Wq = (const float*)d_in[4];
  const float* bq = (const float*)d_in[5];
  const float* Wk = (const float*)d_in[6];
  const float* bk = (const float*)d_in[7];
  float* out = (float*)d_out;

  float* part = (float*)d_ws;                      // 128*40 partials

  proj_kernel<<<PROJ_BLOCKS, 256, 0, stream>>>(K, Wp, part);
  score_kernel<<<dim3(64, 4, 8), 256, 0, stream>>>(Q, K, part, bp, Wq, bq, Wk, bk, out);
}